// Round 2
// baseline (498.242 us; speedup 1.0000x reference)
//
#include <hip/hip_runtime.h>

// Problem constants (fixed by reference setup_inputs)
constexpr int N_NODES = 50000;
constexpr int N_EDGES = 800000;
constexpr int DIM     = 128;
constexpr int DIM4    = DIM / 4;          // 32 float4 columns
constexpr float BN_EPS = 1e-5f;

constexpr int EMPTY = 0x7F7F7F7F;         // > any edge index; min-stable sentinel

// Two-stage select: 16 node chunks x 16 edge chunks, 1024-thread scan blocks.
constexpr int NC = 16;
constexpr int EC = 16;
constexpr int NODES_PER_NC = N_NODES / NC;      // 3125 (50 KB LDS table)
constexpr int EDGES_PER_EC = N_EDGES / EC;      // 50000
constexpr int E4_PER_EC    = EDGES_PER_EC / 4;  // 12500 int4 loads per chunk
constexpr int SEL_THREADS  = 1024;

constexpr int NBUCKETS = 32;              // stats atomic spreading
constexpr int NB_MERGE = (N_NODES + 255) / 256;   // 196 merge blocks in stage B

// Persistent grid for fused conv+BN: 4 blocks/CU x 256 CUs (guaranteed by
// __launch_bounds__(256,4): VGPR<=128, LDS 34KB <= 40KB/block).
constexpr int PGRID = 1024;
constexpr int NODES_PER_TILE = 8;         // 256 threads = 8 nodes x 32 f4-cols
constexpr int CONV_GRID = N_NODES / NODES_PER_TILE;      // 6250 tiles
constexpr int TILES = (CONV_GRID + PGRID - 1) / PGRID;   // 7 (106 blocks get 7)

constexpr int STATS_WORDS = 2 * NBUCKETS * 256;          // 16384 floats
constexpr int ZERO_WORDS  = STATS_WORDS + 4;             // + 2x2 barrier ints

// ---------------- float4 helpers ----------------
__device__ inline float4 f4min(float4 a, float4 b) {
    return make_float4(fminf(a.x,b.x), fminf(a.y,b.y), fminf(a.z,b.z), fminf(a.w,b.w));
}
__device__ inline float4 f4max(float4 a, float4 b) {
    return make_float4(fmaxf(a.x,b.x), fmaxf(a.y,b.y), fmaxf(a.z,b.z), fmaxf(a.w,b.w));
}
__device__ inline float4 f4add(float4 a, float4 b) {
    return make_float4(a.x+b.x, a.y+b.y, a.z+b.z, a.w+b.w);
}
__device__ inline float4 f4fma(float s, float4 v, float4 acc) {   // acc + s*v
    return make_float4(fmaf(s,v.x,acc.x), fmaf(s,v.y,acc.y), fmaf(s,v.z,acc.z), fmaf(s,v.w,acc.w));
}

// ---------------------------------------------------------------------------
// Select stage A: block (nc, ec) scans edge chunk ec with 1024 threads,
// inserts edges whose dst lies in node chunk nc into an LDS top-4 table
// (cascaded LDS atomicMin = concurrent sorted insert), then streams the
// table to tables[ec][node] with plain coalesced stores (one writer/cell).
// ---------------------------------------------------------------------------
__global__ __launch_bounds__(SEL_THREADS)
void select_stageA_kernel(const int* __restrict__ dst,
                          int* __restrict__ tables) {
    __shared__ int slot[NODES_PER_NC * 4];    // 50 KB
    const int nc = blockIdx.x & (NC - 1);
    const int ec = blockIdx.x >> 4;
    const int t  = threadIdx.x;

    for (int i = t; i < NODES_PER_NC * 4; i += SEL_THREADS) slot[i] = EMPTY;
    __syncthreads();

    const int r0 = nc * NODES_PER_NC;
    const int4* __restrict__ dst4 = (const int4*)dst;
    const int base4 = ec * E4_PER_EC;
    for (int i = t; i < E4_PER_EC; i += SEL_THREADS) {
        const int4 d = dst4[base4 + i];
        const int ebase = 4 * (base4 + i);
        #define TRY_INS(comp, off) {                                        \
            unsigned n_ = (unsigned)((comp) - r0);                          \
            if (n_ < (unsigned)NODES_PER_NC) {                              \
                int cur_ = ebase + (off);                                   \
                _Pragma("unroll")                                           \
                for (int j_ = 0; j_ < 4; ++j_) {                            \
                    int old_ = atomicMin(&slot[4 * n_ + j_], cur_);         \
                    if (old_ == EMPTY) break;                               \
                    cur_ = max(cur_, old_);                                 \
                } } }
        TRY_INS(d.x, 0); TRY_INS(d.y, 1); TRY_INS(d.z, 2); TRY_INS(d.w, 3);
        #undef TRY_INS
    }
    __syncthreads();

    int4* __restrict__ out = (int4*)tables + (size_t)ec * N_NODES + r0;
    const int4* __restrict__ sl4 = (const int4*)slot;
    for (int n = t; n < NODES_PER_NC; n += SEL_THREADS) out[n] = sl4[n];
}

// ---------------------------------------------------------------------------
// Select stage B + housekeeping. Blocks [0, NB_MERGE): per node, merge the 16
// per-chunk sorted top-4 lists into the global top-4 (exact), map through src
// (-1 = empty); also zero stats_part + barrier words. Blocks NB_MERGE /
// NB_MERGE+1: blank_p[l] = W_l @ blank_l + b_l (one 128x128 matvec each).
// ---------------------------------------------------------------------------
__global__ __launch_bounds__(256)
void select_stageB_kernel(const int* __restrict__ tables,
                          const int* __restrict__ src,
                          int4* __restrict__ srcs4,
                          float* __restrict__ stats_part,   // zeroed here (+bar)
                          const float* __restrict__ W0, const float* __restrict__ b0,
                          const float* __restrict__ bl0,
                          const float* __restrict__ W1, const float* __restrict__ b1,
                          const float* __restrict__ bl1,
                          float* __restrict__ bp) {
    const int t = threadIdx.x;

    if (blockIdx.x >= NB_MERGE) {         // blank-projection blocks
        if (t < DIM) {
            int l = blockIdx.x - NB_MERGE;
            const float* W  = l ? W1  : W0;
            const float* b  = l ? b1  : b0;
            const float* bl = l ? bl1 : bl0;
            float s = 0.f;
            #pragma unroll 8
            for (int j = 0; j < DIM; ++j) s += W[t * DIM + j] * bl[j];
            bp[l * DIM + t] = s + b[t];
        }
        return;
    }

    const int gid = blockIdx.x * 256 + t;
    if (gid < ZERO_WORDS) stats_part[gid] = 0.f;   // stats + barrier words

    const int v = gid;
    if (v >= N_NODES) return;

    int b0_ = EMPTY, b1_ = EMPTY, b2_ = EMPTY, b3_ = EMPTY;
    #pragma unroll
    for (int ec = 0; ec < EC; ++ec) {
        const int4 c = ((const int4*)tables)[(size_t)ec * N_NODES + v];
        if (c.x >= b3_) continue;         // chunk min can't improve top-4
        #define INS(val) {                                          \
            int x_ = (val);                                         \
            if (x_ < b3_) { b3_ = x_;                               \
                int tm;                                             \
                if (b3_ < b2_) { tm = b2_; b2_ = b3_; b3_ = tm; }   \
                if (b2_ < b1_) { tm = b1_; b1_ = b2_; b2_ = tm; }   \
                if (b1_ < b0_) { tm = b0_; b0_ = b1_; b1_ = tm; } } }
        INS(c.x); INS(c.y); INS(c.z); INS(c.w);
        #undef INS
    }
    int4 o;
    o.x = (b0_ < N_EDGES) ? src[b0_] : -1;
    o.y = (b1_ < N_EDGES) ? src[b1_] : -1;
    o.z = (b2_ < N_EDGES) ? src[b2_] : -1;
    o.w = (b3_ < N_EDGES) ? src[b3_] : -1;
    srcs4[v] = o;
}

// ---------------------------------------------------------------------------
// Fused sort-conv + BN stats + BN apply, one persistent kernel per layer.
// PGRID=1024 blocks (4/CU guaranteed: LB(256,4) caps VGPR at 128; LDS=34KB
// <= 40KB). Conv outputs hv live in LDS across a manual grid barrier (no
// cooperative launch: graph capture rejects it — R0 post-mortem). The last
// arriving block finalizes the bucket stats into final_ (agent-scope stores),
// others spin on a flag, then all apply BN + residual. No h buffer traffic.
// ---------------------------------------------------------------------------
__global__ __launch_bounds__(256, 4)
void conv_bn_fused_kernel(const float* __restrict__ xin,
                          const int4* __restrict__ srcs4,
                          const float* __restrict__ bp,     // 128 floats (this layer)
                          const float* __restrict__ cw,
                          const float* __restrict__ cb,
                          const float* __restrict__ a,
                          const float* __restrict__ g,
                          const float* __restrict__ be,
                          float* __restrict__ stats_part,   // [NBUCKETS][256], pre-zeroed
                          float* __restrict__ final_,       // 256 floats (mu|invstd)
                          int* __restrict__ bar,            // 2 ints, pre-zeroed
                          float* __restrict__ xout) {
    __shared__ float4 hv_lds[TILES][256];     // 28 KB conv outputs
    __shared__ float4 ls[4][32];
    __shared__ float4 ls2[4][32];
    __shared__ float acc[256];
    __shared__ int is_last;

    const int t    = threadIdx.x;
    const int bid  = blockIdx.x;
    const int d4   = t & (DIM4 - 1);
    const int nsub = t >> 5;

    const float4* __restrict__ x4  = (const float4*)xin;
    float4*       __restrict__ xo4 = (float4*)xout;

    const float aa = a[0];
    const float c0 = cw[0], c1 = cw[1], c2 = cw[2], c3 = cw[3];
    const float cbv = cb[0];
    const float4 bpv = ((const float4*)bp)[d4];

    float4 s  = make_float4(0.f, 0.f, 0.f, 0.f);
    float4 s2 = make_float4(0.f, 0.f, 0.f, 0.f);

    #define CSWAP4(p, q) { float4 lo = f4min(p, q); float4 hi = f4max(p, q); p = lo; q = hi; }
    #pragma unroll
    for (int k = 0; k < TILES; ++k) {
        const int tile = k * PGRID + bid;
        if (tile < CONV_GRID) {
            const int v = tile * NODES_PER_TILE + nsub;
            const int4 i0 = srcs4[v];

            float4 g00 = x4[(size_t)max(i0.x, 0) * DIM4 + d4];
            float4 g01 = x4[(size_t)max(i0.y, 0) * DIM4 + d4];
            float4 g02 = x4[(size_t)max(i0.z, 0) * DIM4 + d4];
            float4 g03 = x4[(size_t)max(i0.w, 0) * DIM4 + d4];
            float4 xv  = x4[(size_t)v * DIM4 + d4];

            float4 m0 = (i0.x >= 0) ? g00 : bpv;
            float4 m1 = (i0.y >= 0) ? g01 : bpv;
            float4 m2 = (i0.z >= 0) ? g02 : bpv;
            float4 m3 = (i0.w >= 0) ? g03 : bpv;
            CSWAP4(m0, m1); CSWAP4(m2, m3); CSWAP4(m0, m2); CSWAP4(m1, m3); CSWAP4(m1, m2);
            float4 hv = make_float4(cbv, cbv, cbv, cbv);
            hv = f4fma(c0, m0, hv);
            hv = f4fma(c1, m1, hv);
            hv = f4fma(c2, m2, hv);
            hv = f4fma(c3, m3, hv);
            hv = f4fma(aa, xv, hv);
            hv_lds[k][t] = hv;
            s  = f4add(s, hv);
            s2 = f4add(s2, make_float4(hv.x*hv.x, hv.y*hv.y, hv.z*hv.z, hv.w*hv.w));
        }
    }
    #undef CSWAP4

    // per-block stats reduction -> one bucketed atomic set per block
    s.x  += __shfl_down(s.x, 32);  s.y  += __shfl_down(s.y, 32);
    s.z  += __shfl_down(s.z, 32);  s.w  += __shfl_down(s.w, 32);
    s2.x += __shfl_down(s2.x, 32); s2.y += __shfl_down(s2.y, 32);
    s2.z += __shfl_down(s2.z, 32); s2.w += __shfl_down(s2.w, 32);

    const int wave = t >> 6;
    const int lane = t & 63;
    if (lane < 32) { ls[wave][lane] = s; ls2[wave][lane] = s2; }
    __syncthreads();
    if (t < 32) {
        float* bucket = stats_part + (size_t)(bid & (NBUCKETS - 1)) * 256;
        float4 fs  = f4add(f4add(ls[0][t],  ls[1][t]),  f4add(ls[2][t],  ls[3][t]));
        float4 fs2 = f4add(f4add(ls2[0][t], ls2[1][t]), f4add(ls2[2][t], ls2[3][t]));
        atomicAdd(&bucket[4*t + 0], fs.x);
        atomicAdd(&bucket[4*t + 1], fs.y);
        atomicAdd(&bucket[4*t + 2], fs.z);
        atomicAdd(&bucket[4*t + 3], fs.w);
        atomicAdd(&bucket[DIM + 4*t + 0], fs2.x);
        atomicAdd(&bucket[DIM + 4*t + 1], fs2.y);
        atomicAdd(&bucket[DIM + 4*t + 2], fs2.z);
        atomicAdd(&bucket[DIM + 4*t + 3], fs2.w);
    }
    __syncthreads();                      // block's atomics done before arrival

    // ---- manual grid barrier: arrive; last block finalizes + releases ----
    if (t == 0) {
        __threadfence();
        int arrived = __hip_atomic_fetch_add(&bar[0], 1, __ATOMIC_ACQ_REL,
                                             __HIP_MEMORY_SCOPE_AGENT);
        is_last = (arrived == PGRID - 1) ? 1 : 0;
    }
    __syncthreads();

    constexpr float invN = 1.0f / (float)N_NODES;
    if (is_last) {
        float ssum = 0.f;
        #pragma unroll 8
        for (int k2 = 0; k2 < NBUCKETS; ++k2)
            ssum += __hip_atomic_load(&stats_part[k2 * 256 + t],
                                      __ATOMIC_RELAXED, __HIP_MEMORY_SCOPE_AGENT);
        acc[t] = ssum;
        __syncthreads();
        if (t < 128) {
            float mu = acc[t] * invN;
            float iv = rsqrtf(acc[128 + t] * invN - mu * mu + BN_EPS);
            acc[t]       = mu;
            acc[128 + t] = iv;
            __hip_atomic_store(&final_[t], mu, __ATOMIC_RELAXED, __HIP_MEMORY_SCOPE_AGENT);
            __hip_atomic_store(&final_[128 + t], iv, __ATOMIC_RELAXED, __HIP_MEMORY_SCOPE_AGENT);
        }
        __syncthreads();
        if (t == 0) {
            __threadfence();
            __hip_atomic_store(&bar[1], 1, __ATOMIC_RELEASE, __HIP_MEMORY_SCOPE_AGENT);
        }
    } else {
        if (t == 0) {
            while (__hip_atomic_load(&bar[1], __ATOMIC_ACQUIRE,
                                     __HIP_MEMORY_SCOPE_AGENT) == 0)
                __builtin_amdgcn_s_sleep(2);
        }
        __syncthreads();
        acc[t] = __hip_atomic_load(&final_[t], __ATOMIC_RELAXED, __HIP_MEMORY_SCOPE_AGENT);
        __syncthreads();
    }

    // ---- BN apply + residual straight from LDS-held conv outputs ----
    const float4 mu4 = make_float4(acc[4*d4+0], acc[4*d4+1], acc[4*d4+2], acc[4*d4+3]);
    const float4 iv4 = make_float4(acc[128+4*d4+0], acc[128+4*d4+1],
                                   acc[128+4*d4+2], acc[128+4*d4+3]);
    const float4 gv = ((const float4*)g)[d4];
    const float4 bv = ((const float4*)be)[d4];

    #pragma unroll
    for (int k = 0; k < TILES; ++k) {
        const int tile = k * PGRID + bid;
        if (tile < CONV_GRID) {
            const int v = tile * NODES_PER_TILE + nsub;
            const float4 xv = x4[(size_t)v * DIM4 + d4];   // own cell only
            const float4 hv = hv_lds[k][t];
            float4 o;
            o.x = xv.x + (hv.x - mu4.x) * iv4.x * gv.x + bv.x;
            o.y = xv.y + (hv.y - mu4.y) * iv4.y * gv.y + bv.y;
            o.z = xv.z + (hv.z - mu4.z) * iv4.z * gv.z + bv.z;
            o.w = xv.w + (hv.w - mu4.w) * iv4.w * gv.w + bv.w;
            xo4[(size_t)v * DIM4 + d4] = o;
        }
    }
}

extern "C" void kernel_launch(void* const* d_in, const int* in_sizes, int n_in,
                              void* d_out, int out_size, void* d_ws, size_t ws_size,
                              hipStream_t stream) {
    const float* x0  = (const float*)d_in[0];
    const int*   ei  = (const int*)d_in[1];
    const int*   src = ei;               // edge_index[0]
    const int*   dst = ei + N_EDGES;     // edge_index[1]

    const float* W[2]; const float* b[2]; const float* cw[2]; const float* cb[2];
    const float* a[2]; const float* g[2]; const float* be[2]; const float* blank[2];
    for (int i = 0; i < 2; ++i) {
        int o = 2 + 8 * i;
        W[i]     = (const float*)d_in[o + 0];
        b[i]     = (const float*)d_in[o + 1];
        cw[i]    = (const float*)d_in[o + 2];
        cb[i]    = (const float*)d_in[o + 3];
        a[i]     = (const float*)d_in[o + 4];
        g[i]     = (const float*)d_in[o + 5];
        be[i]    = (const float*)d_in[o + 6];
        blank[i] = (const float*)d_in[o + 7];
    }

    // Workspace layout (re-poisoned 0xAA each call — everything used is
    // written before read): srcs (stage B out), tables (stage A out, dead
    // after stage B), stats_part+bar (zeroed in stage B), final_/bp (written
    // before read).
    char* ws = (char*)d_ws;
    int*   srcs       = (int*)ws;                                 // 4N ints
    int*   tables     = srcs + 4 * N_NODES;                       // 16*4N ints = 12.8 MB
    float* stats_part = (float*)(tables + (size_t)EC * 4 * N_NODES);
    int*   bar        = (int*)(stats_part + STATS_WORDS);         // 2x2 ints
    float* final_     = (float*)(bar + 4);                        // 2x256 floats
    float* bp         = final_ + 512;                             // 2x128 floats

    float* xout = (float*)d_out;

    // ---- two-stage selection (LDS atomics only; streaming merge) ----
    select_stageA_kernel<<<NC * EC, SEL_THREADS, 0, stream>>>(dst, tables);
    select_stageB_kernel<<<NB_MERGE + 2, 256, 0, stream>>>(
        tables, src, (int4*)srcs, stats_part,
        W[0], b[0], blank[0], W[1], b[1], blank[1], bp);

    // ---- two layers, fully fused conv+stats+BN (persistent grid) ----
    for (int l = 0; l < 2; ++l) {
        const float* xin = (l == 0) ? x0 : (const float*)xout;
        conv_bn_fused_kernel<<<PGRID, 256, 0, stream>>>(
            xin, (const int4*)srcs, bp + l * DIM, cw[l], cb[l], a[l],
            g[l], be[l], stats_part + (size_t)l * NBUCKETS * 256,
            final_ + l * 256, bar + l * 2, xout);
    }
}

// Round 3
// 348.431 us; speedup vs baseline: 1.4300x; 1.4300x over previous
//
#include <hip/hip_runtime.h>

// Problem constants (fixed by reference setup_inputs)
constexpr int N_NODES = 50000;
constexpr int N_EDGES = 800000;
constexpr int DIM     = 128;
constexpr int DIM4    = DIM / 4;          // 32 float4 columns
constexpr float BN_EPS = 1e-5f;

constexpr int EMPTY = 0x7F7F7F7F;         // > any edge index; min-stable sentinel

// Two-stage select: 16 node chunks x 16 edge chunks, 1024-thread scan blocks.
constexpr int NC = 16;
constexpr int EC = 16;
constexpr int NODES_PER_NC = N_NODES / NC;      // 3125 (50 KB LDS table)
constexpr int EDGES_PER_EC = N_EDGES / EC;      // 50000
constexpr int E4_PER_EC    = EDGES_PER_EC / 4;  // 12500 int4 loads per chunk
constexpr int SEL_THREADS  = 1024;

constexpr int NBUCKETS = 32;              // stats atomic spreading
constexpr int NB_MERGE = (N_NODES + 255) / 256;   // 196 merge blocks in stage B

// Persistent grid for fused conv+BN: 4 blocks/CU x 256 CUs (guaranteed by
// __launch_bounds__(256,4): VGPR<=128, LDS 34KB <= 40KB/block). PGRID must
// not exceed guaranteed co-residency or the grid barrier deadlocks.
constexpr int PGRID = 1024;
constexpr int NODES_PER_TILE = 8;         // 256 threads = 8 nodes x 32 f4-cols
constexpr int CONV_GRID = N_NODES / NODES_PER_TILE;      // 6250 tiles
constexpr int TILES = (CONV_GRID + PGRID - 1) / PGRID;   // 7 (106 blocks get 7)

constexpr int STATS_WORDS = 2 * NBUCKETS * 256;          // 16384 floats
constexpr int ZERO_WORDS  = STATS_WORDS + 4;             // + 2x2 barrier ints

// ---------------- float4 helpers ----------------
__device__ inline float4 f4min(float4 a, float4 b) {
    return make_float4(fminf(a.x,b.x), fminf(a.y,b.y), fminf(a.z,b.z), fminf(a.w,b.w));
}
__device__ inline float4 f4max(float4 a, float4 b) {
    return make_float4(fmaxf(a.x,b.x), fmaxf(a.y,b.y), fmaxf(a.z,b.z), fmaxf(a.w,b.w));
}
__device__ inline float4 f4add(float4 a, float4 b) {
    return make_float4(a.x+b.x, a.y+b.y, a.z+b.z, a.w+b.w);
}
__device__ inline float4 f4fma(float s, float4 v, float4 acc) {   // acc + s*v
    return make_float4(fmaf(s,v.x,acc.x), fmaf(s,v.y,acc.y), fmaf(s,v.z,acc.z), fmaf(s,v.w,acc.w));
}

// ---------------------------------------------------------------------------
// Select stage A: block (nc, ec) scans edge chunk ec with 1024 threads,
// inserts edges whose dst lies in node chunk nc into an LDS top-4 table
// (cascaded LDS atomicMin = concurrent sorted insert), then streams the
// table to tables[ec][node] with plain coalesced stores (one writer/cell).
// ---------------------------------------------------------------------------
__global__ __launch_bounds__(SEL_THREADS)
void select_stageA_kernel(const int* __restrict__ dst,
                          int* __restrict__ tables) {
    __shared__ int slot[NODES_PER_NC * 4];    // 50 KB
    const int nc = blockIdx.x & (NC - 1);
    const int ec = blockIdx.x >> 4;
    const int t  = threadIdx.x;

    for (int i = t; i < NODES_PER_NC * 4; i += SEL_THREADS) slot[i] = EMPTY;
    __syncthreads();

    const int r0 = nc * NODES_PER_NC;
    const int4* __restrict__ dst4 = (const int4*)dst;
    const int base4 = ec * E4_PER_EC;
    for (int i = t; i < E4_PER_EC; i += SEL_THREADS) {
        const int4 d = dst4[base4 + i];
        const int ebase = 4 * (base4 + i);
        #define TRY_INS(comp, off) {                                        \
            unsigned n_ = (unsigned)((comp) - r0);                          \
            if (n_ < (unsigned)NODES_PER_NC) {                              \
                int cur_ = ebase + (off);                                   \
                _Pragma("unroll")                                           \
                for (int j_ = 0; j_ < 4; ++j_) {                            \
                    int old_ = atomicMin(&slot[4 * n_ + j_], cur_);         \
                    if (old_ == EMPTY) break;                               \
                    cur_ = max(cur_, old_);                                 \
                } } }
        TRY_INS(d.x, 0); TRY_INS(d.y, 1); TRY_INS(d.z, 2); TRY_INS(d.w, 3);
        #undef TRY_INS
    }
    __syncthreads();

    int4* __restrict__ out = (int4*)tables + (size_t)ec * N_NODES + r0;
    const int4* __restrict__ sl4 = (const int4*)slot;
    for (int n = t; n < NODES_PER_NC; n += SEL_THREADS) out[n] = sl4[n];
}

// ---------------------------------------------------------------------------
// Select stage B + housekeeping. Blocks [0, NB_MERGE): per node, merge the 16
// per-chunk sorted top-4 lists into the global top-4 (exact), map through src
// (-1 = empty); also zero stats_part + barrier words. Blocks NB_MERGE /
// NB_MERGE+1: blank_p[l] = W_l @ blank_l + b_l (one 128x128 matvec each).
// ---------------------------------------------------------------------------
__global__ __launch_bounds__(256)
void select_stageB_kernel(const int* __restrict__ tables,
                          const int* __restrict__ src,
                          int4* __restrict__ srcs4,
                          float* __restrict__ stats_part,   // zeroed here (+bar)
                          const float* __restrict__ W0, const float* __restrict__ b0,
                          const float* __restrict__ bl0,
                          const float* __restrict__ W1, const float* __restrict__ b1,
                          const float* __restrict__ bl1,
                          float* __restrict__ bp) {
    const int t = threadIdx.x;

    if (blockIdx.x >= NB_MERGE) {         // blank-projection blocks
        if (t < DIM) {
            int l = blockIdx.x - NB_MERGE;
            const float* W  = l ? W1  : W0;
            const float* b  = l ? b1  : b0;
            const float* bl = l ? bl1 : bl0;
            float s = 0.f;
            #pragma unroll 8
            for (int j = 0; j < DIM; ++j) s += W[t * DIM + j] * bl[j];
            bp[l * DIM + t] = s + b[t];
        }
        return;
    }

    const int gid = blockIdx.x * 256 + t;
    if (gid < ZERO_WORDS) stats_part[gid] = 0.f;   // stats + barrier words

    const int v = gid;
    if (v >= N_NODES) return;

    int b0_ = EMPTY, b1_ = EMPTY, b2_ = EMPTY, b3_ = EMPTY;
    #pragma unroll
    for (int ec = 0; ec < EC; ++ec) {
        const int4 c = ((const int4*)tables)[(size_t)ec * N_NODES + v];
        if (c.x >= b3_) continue;         // chunk min can't improve top-4
        #define INS(val) {                                          \
            int x_ = (val);                                         \
            if (x_ < b3_) { b3_ = x_;                               \
                int tm;                                             \
                if (b3_ < b2_) { tm = b2_; b2_ = b3_; b3_ = tm; }   \
                if (b2_ < b1_) { tm = b1_; b1_ = b2_; b2_ = tm; }   \
                if (b1_ < b0_) { tm = b0_; b0_ = b1_; b1_ = tm; } } }
        INS(c.x); INS(c.y); INS(c.z); INS(c.w);
        #undef INS
    }
    int4 o;
    o.x = (b0_ < N_EDGES) ? src[b0_] : -1;
    o.y = (b1_ < N_EDGES) ? src[b1_] : -1;
    o.z = (b2_ < N_EDGES) ? src[b2_] : -1;
    o.w = (b3_ < N_EDGES) ? src[b3_] : -1;
    srcs4[v] = o;
}

// ---------------------------------------------------------------------------
// Fused sort-conv + BN stats + BN apply, one persistent kernel per layer.
// Manual grid barrier (graph capture rejects cooperative launch — R0).
// R2 lesson: spinning with agent-scope ACQUIRE loads emits a cache
// invalidate per poll, destroying L1/L2 for the still-running tail blocks
// (174us, VALUBusy 2.9%). Fix: RELAXED polls + s_sleep backoff, ONE acquire
// at exit. xv kept in registers across the barrier (no x re-read).
// ---------------------------------------------------------------------------
__global__ __launch_bounds__(256, 4)
void conv_bn_fused_kernel(const float* __restrict__ xin,
                          const int4* __restrict__ srcs4,
                          const float* __restrict__ bp,     // 128 floats (this layer)
                          const float* __restrict__ cw,
                          const float* __restrict__ cb,
                          const float* __restrict__ a,
                          const float* __restrict__ g,
                          const float* __restrict__ be,
                          float* __restrict__ stats_part,   // [NBUCKETS][256], pre-zeroed
                          float* __restrict__ final_,       // 256 floats (mu|invstd)
                          int* __restrict__ bar,            // 2 ints, pre-zeroed
                          float* __restrict__ xout) {
    __shared__ float4 hv_lds[TILES][256];     // 28 KB conv outputs
    __shared__ float4 ls[4][32];
    __shared__ float4 ls2[4][32];
    __shared__ float acc[256];
    __shared__ int is_last;

    const int t    = threadIdx.x;
    const int bid  = blockIdx.x;
    const int d4   = t & (DIM4 - 1);
    const int nsub = t >> 5;

    const float4* __restrict__ x4  = (const float4*)xin;
    float4*       __restrict__ xo4 = (float4*)xout;

    const float aa = a[0];
    const float c0 = cw[0], c1 = cw[1], c2 = cw[2], c3 = cw[3];
    const float cbv = cb[0];
    const float4 bpv = ((const float4*)bp)[d4];

    float4 xv_reg[TILES];                     // residual inputs, live across barrier
    float4 s  = make_float4(0.f, 0.f, 0.f, 0.f);
    float4 s2 = make_float4(0.f, 0.f, 0.f, 0.f);

    #define CSWAP4(p, q) { float4 lo = f4min(p, q); float4 hi = f4max(p, q); p = lo; q = hi; }
    #pragma unroll
    for (int k = 0; k < TILES; ++k) {
        const int tile = k * PGRID + bid;
        if (tile < CONV_GRID) {
            const int v = tile * NODES_PER_TILE + nsub;
            const int4 i0 = srcs4[v];

            float4 g00 = x4[(size_t)max(i0.x, 0) * DIM4 + d4];
            float4 g01 = x4[(size_t)max(i0.y, 0) * DIM4 + d4];
            float4 g02 = x4[(size_t)max(i0.z, 0) * DIM4 + d4];
            float4 g03 = x4[(size_t)max(i0.w, 0) * DIM4 + d4];
            float4 xv  = x4[(size_t)v * DIM4 + d4];
            xv_reg[k] = xv;

            float4 m0 = (i0.x >= 0) ? g00 : bpv;
            float4 m1 = (i0.y >= 0) ? g01 : bpv;
            float4 m2 = (i0.z >= 0) ? g02 : bpv;
            float4 m3 = (i0.w >= 0) ? g03 : bpv;
            CSWAP4(m0, m1); CSWAP4(m2, m3); CSWAP4(m0, m2); CSWAP4(m1, m3); CSWAP4(m1, m2);
            float4 hv = make_float4(cbv, cbv, cbv, cbv);
            hv = f4fma(c0, m0, hv);
            hv = f4fma(c1, m1, hv);
            hv = f4fma(c2, m2, hv);
            hv = f4fma(c3, m3, hv);
            hv = f4fma(aa, xv, hv);
            hv_lds[k][t] = hv;
            s  = f4add(s, hv);
            s2 = f4add(s2, make_float4(hv.x*hv.x, hv.y*hv.y, hv.z*hv.z, hv.w*hv.w));
        }
    }
    #undef CSWAP4

    // per-block stats reduction -> one bucketed atomic set per block
    s.x  += __shfl_down(s.x, 32);  s.y  += __shfl_down(s.y, 32);
    s.z  += __shfl_down(s.z, 32);  s.w  += __shfl_down(s.w, 32);
    s2.x += __shfl_down(s2.x, 32); s2.y += __shfl_down(s2.y, 32);
    s2.z += __shfl_down(s2.z, 32); s2.w += __shfl_down(s2.w, 32);

    const int wave = t >> 6;
    const int lane = t & 63;
    if (lane < 32) { ls[wave][lane] = s; ls2[wave][lane] = s2; }
    __syncthreads();
    if (t < 32) {
        float* bucket = stats_part + (size_t)(bid & (NBUCKETS - 1)) * 256;
        float4 fs  = f4add(f4add(ls[0][t],  ls[1][t]),  f4add(ls[2][t],  ls[3][t]));
        float4 fs2 = f4add(f4add(ls2[0][t], ls2[1][t]), f4add(ls2[2][t], ls2[3][t]));
        atomicAdd(&bucket[4*t + 0], fs.x);
        atomicAdd(&bucket[4*t + 1], fs.y);
        atomicAdd(&bucket[4*t + 2], fs.z);
        atomicAdd(&bucket[4*t + 3], fs.w);
        atomicAdd(&bucket[DIM + 4*t + 0], fs2.x);
        atomicAdd(&bucket[DIM + 4*t + 1], fs2.y);
        atomicAdd(&bucket[DIM + 4*t + 2], fs2.z);
        atomicAdd(&bucket[DIM + 4*t + 3], fs2.w);
    }
    __syncthreads();                      // block's atomics done before arrival

    // ---- manual grid barrier ----
    // Arrive with RELEASE (orders this block's atomics); last block finalizes
    // and publishes. Waiters poll RELAXED (no per-poll cache invalidate!)
    // with sleep backoff; a single ACQUIRE load on exit pairs with the
    // RELEASE store.
    if (t == 0) {
        int arrived = __hip_atomic_fetch_add(&bar[0], 1, __ATOMIC_RELEASE,
                                             __HIP_MEMORY_SCOPE_AGENT);
        is_last = (arrived == PGRID - 1) ? 1 : 0;
    }
    __syncthreads();

    constexpr float invN = 1.0f / (float)N_NODES;
    if (is_last) {
        float ssum = 0.f;
        #pragma unroll 8
        for (int k2 = 0; k2 < NBUCKETS; ++k2)
            ssum += __hip_atomic_load(&stats_part[k2 * 256 + t],
                                      __ATOMIC_RELAXED, __HIP_MEMORY_SCOPE_AGENT);
        acc[t] = ssum;
        __syncthreads();
        if (t < 128) {
            float mu = acc[t] * invN;
            float iv = rsqrtf(acc[128 + t] * invN - mu * mu + BN_EPS);
            acc[t]       = mu;
            acc[128 + t] = iv;
            __hip_atomic_store(&final_[t], mu, __ATOMIC_RELAXED, __HIP_MEMORY_SCOPE_AGENT);
            __hip_atomic_store(&final_[128 + t], iv, __ATOMIC_RELAXED, __HIP_MEMORY_SCOPE_AGENT);
        }
        __syncthreads();
        if (t == 0) {
            __hip_atomic_store(&bar[1], 1, __ATOMIC_RELEASE, __HIP_MEMORY_SCOPE_AGENT);
        }
    } else {
        if (t == 0) {
            while (__hip_atomic_load(&bar[1], __ATOMIC_RELAXED,
                                     __HIP_MEMORY_SCOPE_AGENT) == 0)
                __builtin_amdgcn_s_sleep(8);
            (void)__hip_atomic_load(&bar[1], __ATOMIC_ACQUIRE,
                                    __HIP_MEMORY_SCOPE_AGENT);   // one invalidate
        }
        __syncthreads();
        acc[t] = __hip_atomic_load(&final_[t], __ATOMIC_RELAXED, __HIP_MEMORY_SCOPE_AGENT);
        __syncthreads();
    }

    // ---- BN apply + residual from LDS-held hv and register-held xv ----
    const float4 mu4 = make_float4(acc[4*d4+0], acc[4*d4+1], acc[4*d4+2], acc[4*d4+3]);
    const float4 iv4 = make_float4(acc[128+4*d4+0], acc[128+4*d4+1],
                                   acc[128+4*d4+2], acc[128+4*d4+3]);
    const float4 gv = ((const float4*)g)[d4];
    const float4 bv = ((const float4*)be)[d4];

    #pragma unroll
    for (int k = 0; k < TILES; ++k) {
        const int tile = k * PGRID + bid;
        if (tile < CONV_GRID) {
            const int v = tile * NODES_PER_TILE + nsub;
            const float4 xv = xv_reg[k];
            const float4 hv = hv_lds[k][t];
            float4 o;
            o.x = xv.x + (hv.x - mu4.x) * iv4.x * gv.x + bv.x;
            o.y = xv.y + (hv.y - mu4.y) * iv4.y * gv.y + bv.y;
            o.z = xv.z + (hv.z - mu4.z) * iv4.z * gv.z + bv.z;
            o.w = xv.w + (hv.w - mu4.w) * iv4.w * gv.w + bv.w;
            xo4[(size_t)v * DIM4 + d4] = o;
        }
    }
}

extern "C" void kernel_launch(void* const* d_in, const int* in_sizes, int n_in,
                              void* d_out, int out_size, void* d_ws, size_t ws_size,
                              hipStream_t stream) {
    const float* x0  = (const float*)d_in[0];
    const int*   ei  = (const int*)d_in[1];
    const int*   src = ei;               // edge_index[0]
    const int*   dst = ei + N_EDGES;     // edge_index[1]

    const float* W[2]; const float* b[2]; const float* cw[2]; const float* cb[2];
    const float* a[2]; const float* g[2]; const float* be[2]; const float* blank[2];
    for (int i = 0; i < 2; ++i) {
        int o = 2 + 8 * i;
        W[i]     = (const float*)d_in[o + 0];
        b[i]     = (const float*)d_in[o + 1];
        cw[i]    = (const float*)d_in[o + 2];
        cb[i]    = (const float*)d_in[o + 3];
        a[i]     = (const float*)d_in[o + 4];
        g[i]     = (const float*)d_in[o + 5];
        be[i]    = (const float*)d_in[o + 6];
        blank[i] = (const float*)d_in[o + 7];
    }

    // Workspace layout (re-poisoned 0xAA each call — everything used is
    // written before read): srcs (stage B out), tables (stage A out, dead
    // after stage B), stats_part+bar (zeroed in stage B), final_/bp (written
    // before read).
    char* ws = (char*)d_ws;
    int*   srcs       = (int*)ws;                                 // 4N ints
    int*   tables     = srcs + 4 * N_NODES;                       // 16*4N ints = 12.8 MB
    float* stats_part = (float*)(tables + (size_t)EC * 4 * N_NODES);
    int*   bar        = (int*)(stats_part + STATS_WORDS);         // 2x2 ints
    float* final_     = (float*)(bar + 4);                        // 2x256 floats
    float* bp         = final_ + 512;                             // 2x128 floats

    float* xout = (float*)d_out;

    // ---- two-stage selection (LDS atomics only; streaming merge) ----
    select_stageA_kernel<<<NC * EC, SEL_THREADS, 0, stream>>>(dst, tables);
    select_stageB_kernel<<<NB_MERGE + 2, 256, 0, stream>>>(
        tables, src, (int4*)srcs, stats_part,
        W[0], b[0], blank[0], W[1], b[1], blank[1], bp);

    // ---- two layers, fully fused conv+stats+BN (persistent grid) ----
    for (int l = 0; l < 2; ++l) {
        const float* xin = (l == 0) ? x0 : (const float*)xout;
        conv_bn_fused_kernel<<<PGRID, 256, 0, stream>>>(
            xin, (const int4*)srcs, bp + l * DIM, cw[l], cb[l], a[l],
            g[l], be[l], stats_part + (size_t)l * NBUCKETS * 256,
            final_ + l * 256, bar + l * 2, xout);
    }
}

// Round 4
// 207.175 us; speedup vs baseline: 2.4049x; 1.6818x over previous
//
#include <hip/hip_runtime.h>

// Problem constants (fixed by reference setup_inputs)
constexpr int N_NODES = 50000;
constexpr int N_EDGES = 800000;
constexpr int DIM     = 128;
constexpr int DIM4    = DIM / 4;          // 32 float4 columns
constexpr float BN_EPS = 1e-5f;

constexpr int EMPTY = 0x7F7F7F7F;         // > any edge index; min-stable sentinel

// Two-stage select: 16 node chunks x 16 edge chunks, 1024-thread scan blocks.
constexpr int NC = 16;
constexpr int EC = 16;
constexpr int NODES_PER_NC = N_NODES / NC;      // 3125 (50 KB LDS table)
constexpr int EDGES_PER_EC = N_EDGES / EC;      // 50000
constexpr int E4_PER_EC    = EDGES_PER_EC / 4;  // 12500 int4 loads per chunk
constexpr int SEL_THREADS  = 1024;

constexpr int NBUCKETS = 16;              // stats buckets (16 -> cheap inline reduce)
constexpr int ZERO_WORDS = 2 * NBUCKETS * 256;   // both layers' stats, zeroed in stageB

// Stage B: 2 threads per node, 128 nodes per 256-thread block -> 391 blocks
// (vs 196 before: every CU covered; branchless merge keeps 8 loads in flight).
constexpr int NB_MERGE = (N_NODES + 127) / 128;  // 391

// Conv: proven R10 structure. 256 threads = 8 nodes x 32 f4-cols, 2 iters.
constexpr int NODES_PER_ITER  = 8;
constexpr int NODES_PER_BLOCK = 16;
constexpr int CONV_GRID = N_NODES / NODES_PER_BLOCK;   // 3125 exact, no guard

// ---------------- float4 helpers ----------------
__device__ inline float4 f4min(float4 a, float4 b) {
    return make_float4(fminf(a.x,b.x), fminf(a.y,b.y), fminf(a.z,b.z), fminf(a.w,b.w));
}
__device__ inline float4 f4max(float4 a, float4 b) {
    return make_float4(fmaxf(a.x,b.x), fmaxf(a.y,b.y), fmaxf(a.z,b.z), fmaxf(a.w,b.w));
}
__device__ inline float4 f4add(float4 a, float4 b) {
    return make_float4(a.x+b.x, a.y+b.y, a.z+b.z, a.w+b.w);
}
__device__ inline float4 f4fma(float s, float4 v, float4 acc) {   // acc + s*v
    return make_float4(fmaf(s,v.x,acc.x), fmaf(s,v.y,acc.y), fmaf(s,v.z,acc.z), fmaf(s,v.w,acc.w));
}

// ---------------------------------------------------------------------------
// Select stage A: block (nc, ec) scans edge chunk ec with 1024 threads,
// inserts edges whose dst lies in node chunk nc into an LDS top-4 table
// (cascaded LDS atomicMin = concurrent sorted insert), then streams the
// table to tables[ec][node] with plain coalesced stores (one writer/cell).
// ---------------------------------------------------------------------------
__global__ __launch_bounds__(SEL_THREADS)
void select_stageA_kernel(const int* __restrict__ dst,
                          int* __restrict__ tables) {
    __shared__ int slot[NODES_PER_NC * 4];    // 50 KB
    const int nc = blockIdx.x & (NC - 1);
    const int ec = blockIdx.x >> 4;
    const int t  = threadIdx.x;

    for (int i = t; i < NODES_PER_NC * 4; i += SEL_THREADS) slot[i] = EMPTY;
    __syncthreads();

    const int r0 = nc * NODES_PER_NC;
    const int4* __restrict__ dst4 = (const int4*)dst;
    const int base4 = ec * E4_PER_EC;
    for (int i = t; i < E4_PER_EC; i += SEL_THREADS) {
        const int4 d = dst4[base4 + i];
        const int ebase = 4 * (base4 + i);
        #define TRY_INS(comp, off) {                                        \
            unsigned n_ = (unsigned)((comp) - r0);                          \
            if (n_ < (unsigned)NODES_PER_NC) {                              \
                int cur_ = ebase + (off);                                   \
                _Pragma("unroll")                                           \
                for (int j_ = 0; j_ < 4; ++j_) {                            \
                    int old_ = atomicMin(&slot[4 * n_ + j_], cur_);         \
                    if (old_ == EMPTY) break;                               \
                    cur_ = max(cur_, old_);                                 \
                } } }
        TRY_INS(d.x, 0); TRY_INS(d.y, 1); TRY_INS(d.z, 2); TRY_INS(d.w, 3);
        #undef TRY_INS
    }
    __syncthreads();

    int4* __restrict__ out = (int4*)tables + (size_t)ec * N_NODES + r0;
    const int4* __restrict__ sl4 = (const int4*)slot;
    for (int n = t; n < NODES_PER_NC; n += SEL_THREADS) out[n] = sl4[n];
}

// ---------------------------------------------------------------------------
// Select stage B (rewritten): 2 threads per node. Each thread loads its 8
// chunk-lists UNCONDITIONALLY (8 independent dwordx4 in flight — the old
// early-out branch serialized 16 L2-cold loads), merges them branchlessly
// with a bitonic half-cleaner (lists are sorted ascending; EMPTY sorts
// last), then the thread pair merges via LDS and maps through src.
// Also zeroes stats_part. Blocks NB_MERGE/NB_MERGE+1: blank projections.
// ---------------------------------------------------------------------------
__global__ __launch_bounds__(256)
void select_stageB_kernel(const int* __restrict__ tables,
                          const int* __restrict__ src,
                          int4* __restrict__ srcs4,
                          float* __restrict__ stats_part,   // zeroed here
                          const float* __restrict__ W0, const float* __restrict__ b0,
                          const float* __restrict__ bl0,
                          const float* __restrict__ W1, const float* __restrict__ b1,
                          const float* __restrict__ bl1,
                          float* __restrict__ bp) {
    const int t = threadIdx.x;

    if (blockIdx.x >= NB_MERGE) {         // blank-projection blocks
        if (t < DIM) {
            int l = blockIdx.x - NB_MERGE;
            const float* W  = l ? W1  : W0;
            const float* b  = l ? b1  : b0;
            const float* bl = l ? bl1 : bl0;
            float s = 0.f;
            #pragma unroll 8
            for (int j = 0; j < DIM; ++j) s += W[t * DIM + j] * bl[j];
            bp[l * DIM + t] = s + b[t];
        }
        return;
    }

    const int gid = blockIdx.x * 256 + t;
    if (gid < ZERO_WORDS) stats_part[gid] = 0.f;   // fold the memset

    const int vloc = t & 127;
    const int half = t >> 7;
    int v = blockIdx.x * 128 + vloc;
    const bool valid = (v < N_NODES);
    if (!valid) v = N_NODES - 1;          // clamp: loads stay in-bounds

    // 8 unconditional, independent chunk-list loads (coalesced per half)
    int4 c[8];
    #pragma unroll
    for (int j = 0; j < 8; ++j)
        c[j] = ((const int4*)tables)[(size_t)(half * 8 + j) * N_NODES + v];

    int a0 = c[0].x, a1 = c[0].y, a2 = c[0].z, a3 = c[0].w;
    // Branchless merge of two sorted-4 lists -> lowest 4, sorted.
    // Half-cleaner: m_i = min(a_i, c_{3-i}) (lower half, bitonic), then
    // bitonic-4 sort: CE(0,2) CE(1,3) CE(0,1) CE(2,3).
    #define MERGE4(cx, cy, cz, cw) {                                 \
        int m0 = min(a0, (cw)), m1 = min(a1, (cz));                  \
        int m2 = min(a2, (cy)), m3 = min(a3, (cx));                  \
        int u_;                                                      \
        u_ = min(m0, m2); m2 = max(m0, m2); m0 = u_;                 \
        u_ = min(m1, m3); m3 = max(m1, m3); m1 = u_;                 \
        u_ = min(m0, m1); m1 = max(m0, m1); m0 = u_;                 \
        u_ = min(m2, m3); m3 = max(m2, m3); m2 = u_;                 \
        a0 = m0; a1 = m1; a2 = m2; a3 = m3; }
    #pragma unroll
    for (int j = 1; j < 8; ++j) MERGE4(c[j].x, c[j].y, c[j].z, c[j].w);

    __shared__ int4 xbuf[128];
    if (half) xbuf[vloc] = make_int4(a0, a1, a2, a3);
    __syncthreads();
    if (!half) {
        const int4 o = xbuf[vloc];
        MERGE4(o.x, o.y, o.z, o.w);
        int4 r;
        r.x = (a0 < N_EDGES) ? src[a0] : -1;
        r.y = (a1 < N_EDGES) ? src[a1] : -1;
        r.z = (a2 < N_EDGES) ? src[a2] : -1;
        r.w = (a3 < N_EDGES) ? src[a3] : -1;
        if (valid) srcs4[v] = r;
    }
    #undef MERGE4
}

// ---------------------------------------------------------------------------
// Fused sort-conv + BN statistics (bucketed atomics). Proven R10 structure.
// ---------------------------------------------------------------------------
__global__ __launch_bounds__(256)
void conv_stats_kernel(const float* __restrict__ x,
                       const int4* __restrict__ srcs4,    // per-node 4 gather rows
                       const float* __restrict__ bp,      // 128 floats (this layer)
                       const float* __restrict__ cw,
                       const float* __restrict__ cb,
                       const float* __restrict__ a,
                       float* __restrict__ h,
                       float* __restrict__ stats_part) {  // [NBUCKETS][256]
    const int t    = threadIdx.x;
    const int d4   = t & (DIM4 - 1);
    const int nsub = t >> 5;

    const float4* __restrict__ x4 = (const float4*)x;
    float4*       __restrict__ h4 = (float4*)h;

    const float aa = a[0];
    const float c0 = cw[0], c1 = cw[1], c2 = cw[2], c3 = cw[3];
    const float cbv = cb[0];
    const float4 bpv = ((const float4*)bp)[d4];

    const int v0 = blockIdx.x * NODES_PER_BLOCK + nsub;   // < N_NODES always
    const int v1 = v0 + NODES_PER_ITER;

    const int4 s0 = srcs4[v0];
    const int4 s1 = srcs4[v1];

    // unconditional gathers (clamped row), selects afterwards
    float4 g00 = x4[(size_t)max(s0.x, 0) * DIM4 + d4];
    float4 g01 = x4[(size_t)max(s0.y, 0) * DIM4 + d4];
    float4 g02 = x4[(size_t)max(s0.z, 0) * DIM4 + d4];
    float4 g03 = x4[(size_t)max(s0.w, 0) * DIM4 + d4];
    float4 g10 = x4[(size_t)max(s1.x, 0) * DIM4 + d4];
    float4 g11 = x4[(size_t)max(s1.y, 0) * DIM4 + d4];
    float4 g12 = x4[(size_t)max(s1.z, 0) * DIM4 + d4];
    float4 g13 = x4[(size_t)max(s1.w, 0) * DIM4 + d4];
    float4 xv0 = x4[(size_t)v0 * DIM4 + d4];
    float4 xv1 = x4[(size_t)v1 * DIM4 + d4];

    float4 s  = make_float4(0.f, 0.f, 0.f, 0.f);
    float4 s2 = make_float4(0.f, 0.f, 0.f, 0.f);

    #define CSWAP4(p, q) { float4 lo = f4min(p, q); float4 hi = f4max(p, q); p = lo; q = hi; }
    {
        float4 m0 = (s0.x >= 0) ? g00 : bpv;
        float4 m1 = (s0.y >= 0) ? g01 : bpv;
        float4 m2 = (s0.z >= 0) ? g02 : bpv;
        float4 m3 = (s0.w >= 0) ? g03 : bpv;
        CSWAP4(m0, m1); CSWAP4(m2, m3); CSWAP4(m0, m2); CSWAP4(m1, m3); CSWAP4(m1, m2);
        float4 hv = make_float4(cbv, cbv, cbv, cbv);
        hv = f4fma(c0, m0, hv);
        hv = f4fma(c1, m1, hv);
        hv = f4fma(c2, m2, hv);
        hv = f4fma(c3, m3, hv);
        hv = f4fma(aa, xv0, hv);
        h4[(size_t)v0 * DIM4 + d4] = hv;
        s  = f4add(s, hv);
        s2 = f4add(s2, make_float4(hv.x*hv.x, hv.y*hv.y, hv.z*hv.z, hv.w*hv.w));
    }
    {
        float4 m0 = (s1.x >= 0) ? g10 : bpv;
        float4 m1 = (s1.y >= 0) ? g11 : bpv;
        float4 m2 = (s1.z >= 0) ? g12 : bpv;
        float4 m3 = (s1.w >= 0) ? g13 : bpv;
        CSWAP4(m0, m1); CSWAP4(m2, m3); CSWAP4(m0, m2); CSWAP4(m1, m3); CSWAP4(m1, m2);
        float4 hv = make_float4(cbv, cbv, cbv, cbv);
        hv = f4fma(c0, m0, hv);
        hv = f4fma(c1, m1, hv);
        hv = f4fma(c2, m2, hv);
        hv = f4fma(c3, m3, hv);
        hv = f4fma(aa, xv1, hv);
        h4[(size_t)v1 * DIM4 + d4] = hv;
        s  = f4add(s, hv);
        s2 = f4add(s2, make_float4(hv.x*hv.x, hv.y*hv.y, hv.z*hv.z, hv.w*hv.w));
    }
    #undef CSWAP4

    // intra-wave: lane i += lane i+32 (same d4 column, different node)
    s.x  += __shfl_down(s.x, 32);  s.y  += __shfl_down(s.y, 32);
    s.z  += __shfl_down(s.z, 32);  s.w  += __shfl_down(s.w, 32);
    s2.x += __shfl_down(s2.x, 32); s2.y += __shfl_down(s2.y, 32);
    s2.z += __shfl_down(s2.z, 32); s2.w += __shfl_down(s2.w, 32);

    __shared__ float4 ls[4][32];
    __shared__ float4 ls2[4][32];
    const int wave = t >> 6;
    const int lane = t & 63;
    if (lane < 32) { ls[wave][lane] = s; ls2[wave][lane] = s2; }
    __syncthreads();
    if (t < 32) {
        float* bucket = stats_part + (size_t)(blockIdx.x & (NBUCKETS - 1)) * 256;
        float4 fs  = f4add(f4add(ls[0][t],  ls[1][t]),  f4add(ls[2][t],  ls[3][t]));
        float4 fs2 = f4add(f4add(ls2[0][t], ls2[1][t]), f4add(ls2[2][t], ls2[3][t]));
        atomicAdd(&bucket[4*t + 0], fs.x);
        atomicAdd(&bucket[4*t + 1], fs.y);
        atomicAdd(&bucket[4*t + 2], fs.z);
        atomicAdd(&bucket[4*t + 3], fs.w);
        atomicAdd(&bucket[DIM + 4*t + 0], fs2.x);
        atomicAdd(&bucket[DIM + 4*t + 1], fs2.y);
        atomicAdd(&bucket[DIM + 4*t + 2], fs2.z);
        atomicAdd(&bucket[DIM + 4*t + 3], fs2.w);
    }
}

// ---------------------------------------------------------------------------
// BN apply with inline bucket finalize (replaces reduce_finalize kernel):
// each block sums the 16 bucket partials itself (16 L2-hot loads/thread),
// computes mu/invstd in LDS, then applies BN + residual to its 256 float4s.
// ---------------------------------------------------------------------------
__global__ __launch_bounds__(256)
void bn_apply_kernel(const float* __restrict__ xin,
                     const float* __restrict__ h,
                     const float* __restrict__ stats_part,  // [NBUCKETS][256]
                     const float* __restrict__ g,
                     const float* __restrict__ be,
                     float* __restrict__ xout) {
    __shared__ float acc[256];
    const int t = threadIdx.x;

    float ssum = 0.f;
    #pragma unroll
    for (int k = 0; k < NBUCKETS; ++k) ssum += stats_part[k * 256 + t];
    acc[t] = ssum;
    __syncthreads();
    if (t < 128) {
        constexpr float invN = 1.0f / (float)N_NODES;
        float mu = acc[t] * invN;
        float iv = rsqrtf(acc[128 + t] * invN - mu * mu + BN_EPS);
        acc[t]       = mu;
        acc[128 + t] = iv;
    }
    __syncthreads();

    const int idx = blockIdx.x * 256 + t;   // float4 index; grid exact
    const int d4 = idx & (DIM4 - 1);

    const float4 mu4 = make_float4(acc[4*d4+0], acc[4*d4+1], acc[4*d4+2], acc[4*d4+3]);
    const float4 iv4 = make_float4(acc[128+4*d4+0], acc[128+4*d4+1],
                                   acc[128+4*d4+2], acc[128+4*d4+3]);
    const float4 hv = ((const float4*)h)[idx];
    const float4 xv = ((const float4*)xin)[idx];
    const float4 gv = ((const float4*)g)[d4];
    const float4 bv = ((const float4*)be)[d4];

    float4 o;
    o.x = xv.x + (hv.x - mu4.x) * iv4.x * gv.x + bv.x;
    o.y = xv.y + (hv.y - mu4.y) * iv4.y * gv.y + bv.y;
    o.z = xv.z + (hv.z - mu4.z) * iv4.z * gv.z + bv.z;
    o.w = xv.w + (hv.w - mu4.w) * iv4.w * gv.w + bv.w;
    ((float4*)xout)[idx] = o;
}

extern "C" void kernel_launch(void* const* d_in, const int* in_sizes, int n_in,
                              void* d_out, int out_size, void* d_ws, size_t ws_size,
                              hipStream_t stream) {
    const float* x0  = (const float*)d_in[0];
    const int*   ei  = (const int*)d_in[1];
    const int*   src = ei;               // edge_index[0]
    const int*   dst = ei + N_EDGES;     // edge_index[1]

    const float* W[2]; const float* b[2]; const float* cw[2]; const float* cb[2];
    const float* a[2]; const float* g[2]; const float* be[2]; const float* blank[2];
    for (int i = 0; i < 2; ++i) {
        int o = 2 + 8 * i;
        W[i]     = (const float*)d_in[o + 0];
        b[i]     = (const float*)d_in[o + 1];
        cw[i]    = (const float*)d_in[o + 2];
        cb[i]    = (const float*)d_in[o + 3];
        a[i]     = (const float*)d_in[o + 4];
        g[i]     = (const float*)d_in[o + 5];
        be[i]    = (const float*)d_in[o + 6];
        blank[i] = (const float*)d_in[o + 7];
    }

    // Workspace layout (re-poisoned 0xAA each call — everything used is
    // written before read). tables (stage A output, 12.8 MB) aliases the h
    // region: tables is dead before conv_stats writes h.
    char* ws = (char*)d_ws;
    int*   srcs       = (int*)ws;                                 // 4N ints, int4/node
    float* h          = (float*)(srcs + 4 * N_NODES);             // N*DIM floats = 25.6 MB
    int*   tables     = (int*)h;                                  // alias: 16*4N ints
    float* stats_part = h + (size_t)N_NODES * DIM;                // 2*16*256 floats
    float* bp         = stats_part + ZERO_WORDS;                  // 256 floats

    float* xout = (float*)d_out;

    // ---- two-stage selection ----
    select_stageA_kernel<<<NC * EC, SEL_THREADS, 0, stream>>>(dst, tables);
    select_stageB_kernel<<<NB_MERGE + 2, 256, 0, stream>>>(
        tables, src, (int4*)srcs, stats_part,
        W[0], b[0], blank[0], W[1], b[1], blank[1], bp);

    // ---- two layers: conv+stats, then BN apply w/ inline finalize ----
    for (int l = 0; l < 2; ++l) {
        const float* xin = (l == 0) ? x0 : xout;
        float* sp = stats_part + (size_t)l * NBUCKETS * 256;
        conv_stats_kernel<<<CONV_GRID, 256, 0, stream>>>(
            xin, (const int4*)srcs, bp + l * DIM, cw[l], cb[l], a[l], h, sp);
        bn_apply_kernel<<<(N_NODES * DIM4) / 256, 256, 0, stream>>>(
            xin, h, sp, g[l], be[l], xout);
    }
}